// Round 10
// baseline (585.348 us; speedup 1.0000x reference)
//
#include <hip/hip_runtime.h>
#include <hip/hip_fp16.h>
#include <cstdint>
#include <cstddef>

// Problem constants
#define NB 512
#define NR 1152
#define NC 8
#define NJ 10
#define NO 16
#define NJO 160   // NJ*NO

typedef unsigned int uint32;

union H2U { __half2 h; uint32 u; };

__device__ __forceinline__ uint32 packf16(float a0, float a1) {
    H2U p;
    p.h = __halves2half2(__float2half_rn(a0), __float2half_rn(a1));
    return p.u;
}
__device__ __forceinline__ float2 unpackf16(uint32 w) {
    H2U p; p.u = w;
    return __half22float2(p.h);
}

// ============================================================================
// Kernel 0: transpose x[b][r][c] -> xT[r][b][c]. (R1-exact.)
// ============================================================================
__global__ __launch_bounds__(256) void xpose_kernel(const float* __restrict__ x,
                                                    float* __restrict__ xT) {
    const int r0 = blockIdx.x * 16;
    const int b0 = blockIdx.y * 64;
    const int t  = threadIdx.x;
    __shared__ float tile[16][65][8];

    for (int i = t; i < 2048; i += 256) {
        int b = i >> 5, r = (i >> 1) & 15, h = i & 1;
        float4 v = *(const float4*)&x[(size_t)(b0 + b) * (NR * NC) + (size_t)(r0 + r) * NC + h * 4];
        *(float4*)&tile[r][b][h * 4] = v;
    }
    __syncthreads();
    for (int i = t; i < 2048; i += 256) {
        int r = i >> 7, b = (i >> 1) & 63, h = i & 1;
        float4 v = *(const float4*)&tile[r][b][h * 4];
        *(float4*)&xT[(size_t)(r0 + r) * (NB * NC) + (size_t)(b0 + b) * NC + h * 4] = v;
    }
}

// ============================================================================
// Kernel 1: u_hat -> f16 pairs. OCTO-GROUPED rows (R5-exact).
// Row (b,r) = 80 u32; slot ni = g*10 + 2*jloc + d, g = qt*2 + jh,
// j = jh*5 + jloc, holds o-pair (4qt+2d, 4qt+2d+1) of capsule j.
// ============================================================================
__global__ __launch_bounds__(320) void uhat_kernel(const float* __restrict__ xT,
                                                   const float* __restrict__ W,
                                                   uint32* __restrict__ u) {
    const int r = blockIdx.x;
    const int t = threadIdx.x;

    __shared__ float Ws[NC][NJO + 4];   // stride 164: staging conflict-free
    __shared__ float xs[NB][NC];

    for (int i = t; i < NJO * NC; i += 320) {
        Ws[i & 7][i >> 3] = W[(size_t)r * (NJO * NC) + i];
    }
    {
        const float4* xsrc = (const float4*)(xT + (size_t)r * (NB * NC));
        float4* xdst = (float4*)&xs[0][0];
        for (int i = t; i < (NB * NC) / 4; i += 320) xdst[i] = xsrc[i];
    }
    __syncthreads();

    const int ni   = t % 80;   // u32 slot in the permuted row
    const int half = t / 80;
    const int g    = ni / 10;        // (qt,jh) group
    const int rem  = ni % 10;
    const int qt   = g >> 1;
    const int jh   = g & 1;
    const int j    = jh * 5 + (rem >> 1);
    const int d    = rem & 1;
    const int jo0  = 16 * j + 4 * qt + 2 * d;   // o index pair (jo0, jo0+1)

    float w0[8], w1[8];
#pragma unroll
    for (int c = 0; c < 8; ++c) {
        w0[c] = Ws[c][jo0];
        w1[c] = Ws[c][jo0 + 1];
    }

    for (int b = half; b < NB; b += 4) {
        const float4* xp = (const float4*)xs[b];
        float4 xa = xp[0], xb = xp[1];
        float a0 = w0[0] * xa.x + w0[1] * xa.y + w0[2] * xa.z + w0[3] * xa.w
                 + w0[4] * xb.x + w0[5] * xb.y + w0[6] * xb.z + w0[7] * xb.w;
        float a1 = w1[0] * xa.x + w1[1] * xa.y + w1[2] * xa.z + w1[3] * xa.w
                 + w1[4] * xb.x + w1[5] * xb.y + w1[6] * xb.z + w1[7] * xb.w;
        u[(size_t)(b * NR + r) * 80 + ni] = packf16(a0, a1);
    }
}

// ============================================================================
// Merged routing kernel, R9: back to THREE in-kernel iterations (s0gemm arc
// was net-negative: ~50 us kernel+launch cost vs 21 us routing savings).
// Occupancy attack: 1024 threads (16 waves), __launch_bounds__(1024,8) ->
// 2 blocks/CU = 32 waves/CU (HW max; was ~18). Routing has always been
// latency-bound (occ 24%, VALU ~35%, HBM ~33%); 1.78x resident waves is the
// remaining TLP lever. Same 8-lanes/row math as R5 (masks intra-wave), each
// of 128 lane-groups handles 9 rows (128*9=1152) with the depth-1 uint2
// ping-pong (proven no-spill at VGPR 64).
// ============================================================================
#define LOADROW(Q0, Q1, Q2, Q3, Q4, ROW)                                      \
    {                                                                         \
        const uint32* p_ = ubase + (size_t)(ROW) * 80;                        \
        Q0 = *(const uint2*)(p_);     Q1 = *(const uint2*)(p_ + 2);           \
        Q2 = *(const uint2*)(p_ + 4); Q3 = *(const uint2*)(p_ + 6);           \
        Q4 = *(const uint2*)(p_ + 8);                                         \
    }

#define PROCESS(Q0, Q1, Q2, Q3, Q4)                                           \
    {                                                                         \
        uint32 ur[10];                                                        \
        ur[0] = Q0.x; ur[1] = Q0.y; ur[2] = Q1.x; ur[3] = Q1.y;               \
        ur[4] = Q2.x; ur[5] = Q2.y; ur[6] = Q3.x; ur[7] = Q3.y;               \
        ur[8] = Q4.x; ur[9] = Q4.y;                                           \
        float cj[5];                                                          \
        if (it == 0) {                                                        \
            _Pragma("unroll")                                                 \
            for (int jl = 0; jl < 5; ++jl) cj[jl] = 0.1f;                     \
        } else {                                                              \
            float sum = 0.0f;                                                 \
            _Pragma("unroll")                                                 \
            for (int jl = 0; jl < 5; ++jl) {                                  \
                float2 ua = unpackf16(ur[2 * jl]);                            \
                float2 ub = unpackf16(ur[2 * jl + 1]);                        \
                float4 vv = *(const float4*)&vls[vbase + 16 * jl];            \
                float pj = ua.x * vv.x + ua.y * vv.y + ub.x * vv.z + ub.y * vv.w; \
                pj += __shfl_xor(pj, 1);                                      \
                pj += __shfl_xor(pj, 2);                                      \
                float e = __expf(pj);                                         \
                cj[jl] = e;                                                   \
                sum += e;                                                     \
            }                                                                 \
            sum += __shfl_xor(sum, 4);                                        \
            float inv = 1.0f / sum;                                           \
            _Pragma("unroll")                                                 \
            for (int jl = 0; jl < 5; ++jl) cj[jl] *= inv;                     \
        }                                                                     \
        _Pragma("unroll")                                                     \
        for (int jl = 0; jl < 5; ++jl) {                                      \
            float2 ua = unpackf16(ur[2 * jl]);                                \
            float2 ub = unpackf16(ur[2 * jl + 1]);                            \
            acc[4 * jl + 0] += cj[jl] * ua.x;                                 \
            acc[4 * jl + 1] += cj[jl] * ua.y;                                 \
            acc[4 * jl + 2] += cj[jl] * ub.x;                                 \
            acc[4 * jl + 3] += cj[jl] * ub.y;                                 \
        }                                                                     \
    }

__global__ __launch_bounds__(1024, 8) void routing_kernel(const uint32* __restrict__ u,
                                                          float* __restrict__ outp) {
    const int b    = blockIdx.x;
    const int t    = threadIdx.x;
    const int w    = t >> 6;          // wave 0..15
    const int l    = t & 63;
    const int qt   = l & 3;           // o-quarter
    const int jh   = (l >> 2) & 1;    // capsule half
    const int mloc = l >> 3;          // group within wave (0..7)
    const int g    = qt * 2 + jh;     // u32-group in row

    __shared__ float sl[NJO];     // s accumulator
    __shared__ float vls[NJO];    // current v-sum (fp32), read by dot
    __shared__ float vaccl[NJO];  // running v0+v1 (fp32)

    for (int i = t; i < NJO; i += 1024) sl[i] = 0.0f;
    __syncthreads();

    const uint32* ubase = u + (size_t)b * (NR * 80) + g * 10;
    const int vbase = jh * 80 + qt * 4;     // vls[16*(jh*5+jl) + 4*qt]
    const int gid   = w * 8 + mloc;         // lane-group 0..127; rows gid + 128*c9

#pragma unroll 1
    for (int it = 0; it < 3; ++it) {
        float acc[20];
#pragma unroll
        for (int i = 0; i < 20; ++i) acc[i] = 0.0f;

        uint2 qa0, qa1, qa2, qa3, qa4;
        uint2 qb0, qb1, qb2, qb3, qb4;

        LOADROW(qa0, qa1, qa2, qa3, qa4, gid)

#pragma unroll 1
        for (int c9 = 0; c9 < 8; c9 += 2) {
            LOADROW(qb0, qb1, qb2, qb3, qb4, gid + (size_t)(c9 + 1) * 128)
            PROCESS(qa0, qa1, qa2, qa3, qa4)
            LOADROW(qa0, qa1, qa2, qa3, qa4, gid + (size_t)(c9 + 2) * 128)
            PROCESS(qb0, qb1, qb2, qb3, qb4)
        }
        PROCESS(qa0, qa1, qa2, qa3, qa4)   // row gid + 8*128 (9th row)

        // ---- reduce-scatter among the 8 same-(qt,jh) lanes (masks 8,16,32) ----
        float a[12];
        {
            const int bit = (l >> 3) & 1;
#pragma unroll
            for (int i = 0; i < 12; ++i) {
                float lo = acc[i];
                float hi = (i + 12 < 20) ? acc[i + 12] : 0.0f;
                float send = bit ? lo : hi;
                float recv = __shfl_xor(send, 8);
                a[i] = (bit ? hi : lo) + recv;
            }
        }
#pragma unroll
        for (int st = 1; st < 3; ++st) {
            const int h = 12 >> st;              // 6,3
            const int bit = (l >> (3 + st)) & 1;
#pragma unroll
            for (int i = 0; i < 6; ++i) {
                if (i < h) {
                    float send = bit ? a[i] : a[i + h];
                    float recv = __shfl_xor(send, 8 << st);
                    a[i] = (bit ? a[i + h] : a[i]) + recv;
                }
            }
        }
        const int base = 3 * (__brev((uint32)mloc) >> 29);
#pragma unroll
        for (int i = 0; i < 3; ++i) {
            int aidx = base + i;
            if (aidx < 20) {
                int jl = aidx >> 2, e = aidx & 3;
                atomicAdd(&sl[16 * (jh * 5 + jl) + 4 * qt + e], a[i]);
            }
        }
        __syncthreads();

        // ---- in-block squash: thread p<80 owns o-pair (2p, 2p+1) ----
        if (t < 80) {
            float2 sv = *(const float2*)&sl[2 * t];
            float sq = sv.x * sv.x + sv.y * sv.y;
#pragma unroll
            for (int off = 1; off < 8; off <<= 1) sq += __shfl_xor(sq, off, 8);
            float scale = (sq / (1.0f + sq)) * rsqrtf(sq + 1e-8f);
            float vx = sv.x * scale, vy = sv.y * scale;
            if (it == 2) {
                *(float2*)&outp[b * NJO + 2 * t] = make_float2(vx, vy);
            } else {
                float2 va;
                if (it == 0) va = make_float2(vx, vy);
                else {
                    va = *(const float2*)&vaccl[2 * t];
                    va.x += vx; va.y += vy;
                }
                *(float2*)&vaccl[2 * t] = va;
                *(float2*)&vls[2 * t]   = va;
            }
        }
        __syncthreads();
        if (it < 2) {
            for (int i = t; i < NJO; i += 1024) sl[i] = 0.0f;
            __syncthreads();
        }
    }
}

// ============================================================================
extern "C" void kernel_launch(void* const* d_in, const int* in_sizes, int n_in,
                              void* d_out, int out_size, void* d_ws, size_t ws_size,
                              hipStream_t stream) {
    (void)in_sizes; (void)n_in; (void)out_size; (void)ws_size;

    const float* x = (const float*)d_in[0];  // [B,R,C]
    const float* W = (const float*)d_in[1];  // [R,J,O,C]
    float* out = (float*)d_out;              // [B,J,O,1] fp32

    char* ws = (char*)d_ws;
    const size_t XBYTES = (size_t)NR * NB * NC * 4;   // 18,874,368
    float*  xT = (float*)ws;
    uint32* u  = (uint32*)(ws + XBYTES);              // [B,R,80] f16 pairs

    xpose_kernel<<<dim3(NR / 16, NB / 64), 256, 0, stream>>>(x, xT);
    uhat_kernel<<<NR, 320, 0, stream>>>(xT, W, u);
    routing_kernel<<<NB, 1024, 0, stream>>>(u, out);
}

// Round 11
// 225.484 us; speedup vs baseline: 2.5960x; 2.5960x over previous
//
#include <hip/hip_runtime.h>
#include <hip/hip_fp16.h>
#include <cstdint>
#include <cstddef>

// Problem constants
#define NB 512
#define NR 1152
#define NC 8
#define NJ 10
#define NO 16
#define NJO 160   // NJ*NO

typedef unsigned int uint32;

union H2U { __half2 h; uint32 u; };

__device__ __forceinline__ uint32 packf16(float a0, float a1) {
    H2U p;
    p.h = __halves2half2(__float2half_rn(a0), __float2half_rn(a1));
    return p.u;
}
__device__ __forceinline__ float2 unpackf16(uint32 w) {
    H2U p; p.u = w;
    return __half22float2(p.h);
}

// ============================================================================
// Kernel 0: transpose x[b][r][c] -> xT[r][b][c]. (R1-exact.)
// ============================================================================
__global__ __launch_bounds__(256) void xpose_kernel(const float* __restrict__ x,
                                                    float* __restrict__ xT) {
    const int r0 = blockIdx.x * 16;
    const int b0 = blockIdx.y * 64;
    const int t  = threadIdx.x;
    __shared__ float tile[16][65][8];

    for (int i = t; i < 2048; i += 256) {
        int b = i >> 5, r = (i >> 1) & 15, h = i & 1;
        float4 v = *(const float4*)&x[(size_t)(b0 + b) * (NR * NC) + (size_t)(r0 + r) * NC + h * 4];
        *(float4*)&tile[r][b][h * 4] = v;
    }
    __syncthreads();
    for (int i = t; i < 2048; i += 256) {
        int r = i >> 7, b = (i >> 1) & 63, h = i & 1;
        float4 v = *(const float4*)&tile[r][b][h * 4];
        *(float4*)&xT[(size_t)(r0 + r) * (NB * NC) + (size_t)(b0 + b) * NC + h * 4] = v;
    }
}

// ============================================================================
// Kernel 1: u_hat -> f16 pairs. OCTO-GROUPED rows (R5-exact).
// Row (b,r) = 80 u32; slot ni = g*10 + 2*jloc + d, g = qt*2 + jh,
// j = jh*5 + jloc, holds o-pair (4qt+2d, 4qt+2d+1) of capsule j.
// ============================================================================
__global__ __launch_bounds__(320) void uhat_kernel(const float* __restrict__ xT,
                                                   const float* __restrict__ W,
                                                   uint32* __restrict__ u) {
    const int r = blockIdx.x;
    const int t = threadIdx.x;

    __shared__ float Ws[NC][NJO + 4];   // stride 164: staging conflict-free
    __shared__ float xs[NB][NC];

    for (int i = t; i < NJO * NC; i += 320) {
        Ws[i & 7][i >> 3] = W[(size_t)r * (NJO * NC) + i];
    }
    {
        const float4* xsrc = (const float4*)(xT + (size_t)r * (NB * NC));
        float4* xdst = (float4*)&xs[0][0];
        for (int i = t; i < (NB * NC) / 4; i += 320) xdst[i] = xsrc[i];
    }
    __syncthreads();

    const int ni   = t % 80;   // u32 slot in the permuted row
    const int half = t / 80;
    const int g    = ni / 10;        // (qt,jh) group
    const int rem  = ni % 10;
    const int qt   = g >> 1;
    const int jh   = g & 1;
    const int j    = jh * 5 + (rem >> 1);
    const int d    = rem & 1;
    const int jo0  = 16 * j + 4 * qt + 2 * d;   // o index pair (jo0, jo0+1)

    float w0[8], w1[8];
#pragma unroll
    for (int c = 0; c < 8; ++c) {
        w0[c] = Ws[c][jo0];
        w1[c] = Ws[c][jo0 + 1];
    }

    for (int b = half; b < NB; b += 4) {
        const float4* xp = (const float4*)xs[b];
        float4 xa = xp[0], xb = xp[1];
        float a0 = w0[0] * xa.x + w0[1] * xa.y + w0[2] * xa.z + w0[3] * xa.w
                 + w0[4] * xb.x + w0[5] * xb.y + w0[6] * xb.z + w0[7] * xb.w;
        float a1 = w1[0] * xa.x + w1[1] * xa.y + w1[2] * xa.z + w1[3] * xa.w
                 + w1[4] * xb.x + w1[5] * xb.y + w1[6] * xb.z + w1[7] * xb.w;
        u[(size_t)(b * NR + r) * 80 + ni] = packf16(a0, a1);
    }
}

// ============================================================================
// Merged routing kernel, R10: 1024 threads, max occupancy, NO ping-pong.
// R9 post-mortem: __launch_bounds__(1024,8) + ping-pong => 70-reg working set
// vs 64-reg cap => VGPR 32 + 1.6 GB scratch spill (WRITE 802 MB). But the
// occupancy mechanism itself WORKED (81% resident). At 32 waves/CU, TLP
// alone covers load latency (8 waves/SIMD x ~140cy/row issue ~ 1120 cy
// >> 500-900 cy L3/HBM latency), so ILP ping-pong is unnecessary: plain
// load->process per row. Working set ~50 VGPR < 64 cap => no spill.
// 8 lanes/row (qt,jh), 128 lane-groups x 9 rows = 1152.
// ============================================================================
#define LOADROW(Q0, Q1, Q2, Q3, Q4, ROW)                                      \
    {                                                                         \
        const uint32* p_ = ubase + (size_t)(ROW) * 80;                        \
        Q0 = *(const uint2*)(p_);     Q1 = *(const uint2*)(p_ + 2);           \
        Q2 = *(const uint2*)(p_ + 4); Q3 = *(const uint2*)(p_ + 6);           \
        Q4 = *(const uint2*)(p_ + 8);                                         \
    }

#define PROCESS(Q0, Q1, Q2, Q3, Q4)                                           \
    {                                                                         \
        uint32 ur[10];                                                        \
        ur[0] = Q0.x; ur[1] = Q0.y; ur[2] = Q1.x; ur[3] = Q1.y;               \
        ur[4] = Q2.x; ur[5] = Q2.y; ur[6] = Q3.x; ur[7] = Q3.y;               \
        ur[8] = Q4.x; ur[9] = Q4.y;                                           \
        float cj[5];                                                          \
        if (it == 0) {                                                        \
            _Pragma("unroll")                                                 \
            for (int jl = 0; jl < 5; ++jl) cj[jl] = 0.1f;                     \
        } else {                                                              \
            float sum = 0.0f;                                                 \
            _Pragma("unroll")                                                 \
            for (int jl = 0; jl < 5; ++jl) {                                  \
                float2 ua = unpackf16(ur[2 * jl]);                            \
                float2 ub = unpackf16(ur[2 * jl + 1]);                        \
                float4 vv = *(const float4*)&vls[vbase + 16 * jl];            \
                float pj = ua.x * vv.x + ua.y * vv.y + ub.x * vv.z + ub.y * vv.w; \
                pj += __shfl_xor(pj, 1);                                      \
                pj += __shfl_xor(pj, 2);                                      \
                float e = __expf(pj);                                         \
                cj[jl] = e;                                                   \
                sum += e;                                                     \
            }                                                                 \
            sum += __shfl_xor(sum, 4);                                        \
            float inv = 1.0f / sum;                                           \
            _Pragma("unroll")                                                 \
            for (int jl = 0; jl < 5; ++jl) cj[jl] *= inv;                     \
        }                                                                     \
        _Pragma("unroll")                                                     \
        for (int jl = 0; jl < 5; ++jl) {                                      \
            float2 ua = unpackf16(ur[2 * jl]);                                \
            float2 ub = unpackf16(ur[2 * jl + 1]);                            \
            acc[4 * jl + 0] += cj[jl] * ua.x;                                 \
            acc[4 * jl + 1] += cj[jl] * ua.y;                                 \
            acc[4 * jl + 2] += cj[jl] * ub.x;                                 \
            acc[4 * jl + 3] += cj[jl] * ub.y;                                 \
        }                                                                     \
    }

__global__ __launch_bounds__(1024, 8) void routing_kernel(const uint32* __restrict__ u,
                                                          float* __restrict__ outp) {
    const int b    = blockIdx.x;
    const int t    = threadIdx.x;
    const int w    = t >> 6;          // wave 0..15
    const int l    = t & 63;
    const int qt   = l & 3;           // o-quarter
    const int jh   = (l >> 2) & 1;    // capsule half
    const int mloc = l >> 3;          // group within wave (0..7)
    const int g    = qt * 2 + jh;     // u32-group in row

    __shared__ float sl[NJO];     // s accumulator
    __shared__ float vls[NJO];    // current v-sum (fp32), read by dot
    __shared__ float vaccl[NJO];  // running v0+v1 (fp32)

    for (int i = t; i < NJO; i += 1024) sl[i] = 0.0f;
    __syncthreads();

    const uint32* ubase = u + (size_t)b * (NR * 80) + g * 10;
    const int vbase = jh * 80 + qt * 4;     // vls[16*(jh*5+jl) + 4*qt]
    const int gid   = w * 8 + mloc;         // lane-group 0..127; rows gid + 128*c9

#pragma unroll 1
    for (int it = 0; it < 3; ++it) {
        float acc[20];
#pragma unroll
        for (int i = 0; i < 20; ++i) acc[i] = 0.0f;

#pragma unroll 1
        for (int c9 = 0; c9 < 9; ++c9) {
            uint2 q0, q1, q2, q3, q4;
            LOADROW(q0, q1, q2, q3, q4, gid + (size_t)c9 * 128)
            PROCESS(q0, q1, q2, q3, q4)
        }

        // ---- reduce-scatter among the 8 same-(qt,jh) lanes (masks 8,16,32) ----
        float a[12];
        {
            const int bit = (l >> 3) & 1;
#pragma unroll
            for (int i = 0; i < 12; ++i) {
                float lo = acc[i];
                float hi = (i + 12 < 20) ? acc[i + 12] : 0.0f;
                float send = bit ? lo : hi;
                float recv = __shfl_xor(send, 8);
                a[i] = (bit ? hi : lo) + recv;
            }
        }
#pragma unroll
        for (int st = 1; st < 3; ++st) {
            const int h = 12 >> st;              // 6,3
            const int bit = (l >> (3 + st)) & 1;
#pragma unroll
            for (int i = 0; i < 6; ++i) {
                if (i < h) {
                    float send = bit ? a[i] : a[i + h];
                    float recv = __shfl_xor(send, 8 << st);
                    a[i] = (bit ? a[i + h] : a[i]) + recv;
                }
            }
        }
        const int base = 3 * (__brev((uint32)mloc) >> 29);
#pragma unroll
        for (int i = 0; i < 3; ++i) {
            int aidx = base + i;
            if (aidx < 20) {
                int jl = aidx >> 2, e = aidx & 3;
                atomicAdd(&sl[16 * (jh * 5 + jl) + 4 * qt + e], a[i]);
            }
        }
        __syncthreads();

        // ---- in-block squash: thread p<80 owns o-pair (2p, 2p+1) ----
        if (t < 80) {
            float2 sv = *(const float2*)&sl[2 * t];
            float sq = sv.x * sv.x + sv.y * sv.y;
#pragma unroll
            for (int off = 1; off < 8; off <<= 1) sq += __shfl_xor(sq, off, 8);
            float scale = (sq / (1.0f + sq)) * rsqrtf(sq + 1e-8f);
            float vx = sv.x * scale, vy = sv.y * scale;
            if (it == 2) {
                *(float2*)&outp[b * NJO + 2 * t] = make_float2(vx, vy);
            } else {
                float2 va;
                if (it == 0) va = make_float2(vx, vy);
                else {
                    va = *(const float2*)&vaccl[2 * t];
                    va.x += vx; va.y += vy;
                }
                *(float2*)&vaccl[2 * t] = va;
                *(float2*)&vls[2 * t]   = va;
            }
        }
        __syncthreads();
        if (it < 2) {
            for (int i = t; i < NJO; i += 1024) sl[i] = 0.0f;
            __syncthreads();
        }
    }
}

// ============================================================================
extern "C" void kernel_launch(void* const* d_in, const int* in_sizes, int n_in,
                              void* d_out, int out_size, void* d_ws, size_t ws_size,
                              hipStream_t stream) {
    (void)in_sizes; (void)n_in; (void)out_size; (void)ws_size;

    const float* x = (const float*)d_in[0];  // [B,R,C]
    const float* W = (const float*)d_in[1];  // [R,J,O,C]
    float* out = (float*)d_out;              // [B,J,O,1] fp32

    char* ws = (char*)d_ws;
    const size_t XBYTES = (size_t)NR * NB * NC * 4;   // 18,874,368
    float*  xT = (float*)ws;
    uint32* u  = (uint32*)(ws + XBYTES);              // [B,R,80] f16 pairs

    xpose_kernel<<<dim3(NR / 16, NB / 64), 256, 0, stream>>>(x, xT);
    uhat_kernel<<<NR, 320, 0, stream>>>(xT, W, u);
    routing_kernel<<<NB, 1024, 0, stream>>>(u, out);
}

// Round 14
// 212.757 us; speedup vs baseline: 2.7513x; 1.0598x over previous
//
#include <hip/hip_runtime.h>
#include <hip/hip_fp16.h>
#include <cstdint>
#include <cstddef>

// Problem constants
#define NB 512
#define NR 1152
#define NC 8
#define NJ 10
#define NO 16
#define NJO 160   // NJ*NO

typedef unsigned int uint32;

union H2U { __half2 h; uint32 u; };

__device__ __forceinline__ uint32 packf16(float a0, float a1) {
    H2U p;
    p.h = __halves2half2(__float2half_rn(a0), __float2half_rn(a1));
    return p.u;
}
__device__ __forceinline__ float2 unpackf16(uint32 w) {
    H2U p; p.u = w;
    return __half22float2(p.h);
}

// ============================================================================
// Kernel 0: transpose x[b][r][c] -> xT[r][b][c]. (R1-exact.)
// ============================================================================
__global__ __launch_bounds__(256) void xpose_kernel(const float* __restrict__ x,
                                                    float* __restrict__ xT) {
    const int r0 = blockIdx.x * 16;
    const int b0 = blockIdx.y * 64;
    const int t  = threadIdx.x;
    __shared__ float tile[16][65][8];

    for (int i = t; i < 2048; i += 256) {
        int b = i >> 5, r = (i >> 1) & 15, h = i & 1;
        float4 v = *(const float4*)&x[(size_t)(b0 + b) * (NR * NC) + (size_t)(r0 + r) * NC + h * 4];
        *(float4*)&tile[r][b][h * 4] = v;
    }
    __syncthreads();
    for (int i = t; i < 2048; i += 256) {
        int r = i >> 7, b = (i >> 1) & 63, h = i & 1;
        float4 v = *(const float4*)&tile[r][b][h * 4];
        *(float4*)&xT[(size_t)(r0 + r) * (NB * NC) + (size_t)(b0 + b) * NC + h * 4] = v;
    }
}

// ============================================================================
// Kernel 1: u_hat -> f16 pairs. OCTO-GROUPED rows (R5-exact).
// Row (b,r) = 80 u32; slot ni = g*10 + 2*jloc + d, g = qt*2 + jh,
// j = jh*5 + jloc, holds o-pair (4qt+2d, 4qt+2d+1) of capsule j.
// ============================================================================
__global__ __launch_bounds__(320) void uhat_kernel(const float* __restrict__ xT,
                                                   const float* __restrict__ W,
                                                   uint32* __restrict__ u) {
    const int r = blockIdx.x;
    const int t = threadIdx.x;

    __shared__ float Ws[NC][NJO + 4];   // stride 164: staging conflict-free
    __shared__ float xs[NB][NC];

    for (int i = t; i < NJO * NC; i += 320) {
        Ws[i & 7][i >> 3] = W[(size_t)r * (NJO * NC) + i];
    }
    {
        const float4* xsrc = (const float4*)(xT + (size_t)r * (NB * NC));
        float4* xdst = (float4*)&xs[0][0];
        for (int i = t; i < (NB * NC) / 4; i += 320) xdst[i] = xsrc[i];
    }
    __syncthreads();

    const int ni   = t % 80;   // u32 slot in the permuted row
    const int half = t / 80;
    const int g    = ni / 10;        // (qt,jh) group
    const int rem  = ni % 10;
    const int qt   = g >> 1;
    const int jh   = g & 1;
    const int j    = jh * 5 + (rem >> 1);
    const int d    = rem & 1;
    const int jo0  = 16 * j + 4 * qt + 2 * d;   // o index pair (jo0, jo0+1)

    float w0[8], w1[8];
#pragma unroll
    for (int c = 0; c < 8; ++c) {
        w0[c] = Ws[c][jo0];
        w1[c] = Ws[c][jo0 + 1];
    }

    for (int b = half; b < NB; b += 4) {
        const float4* xp = (const float4*)xs[b];
        float4 xa = xp[0], xb = xp[1];
        float a0 = w0[0] * xa.x + w0[1] * xa.y + w0[2] * xa.z + w0[3] * xa.w
                 + w0[4] * xb.x + w0[5] * xb.y + w0[6] * xb.z + w0[7] * xb.w;
        float a1 = w1[0] * xa.x + w1[1] * xa.y + w1[2] * xa.z + w1[3] * xa.w
                 + w1[4] * xb.x + w1[5] * xb.y + w1[6] * xb.z + w1[7] * xb.w;
        u[(size_t)(b * NR + r) * 80 + ni] = packf16(a0, a1);
    }
}

// ============================================================================
// Merged routing kernel, R13: 1024 threads, max occupancy, NO ping-pong,
// __launch_bounds__(1024) -- single-arg form. For a 16-wave block this
// implies the SAME VGPR<=128 cap as (1024,4) (all 16 waves must co-reside:
// 4 waves/SIMD), but drops the only untested token after two container
// failures (R12/R13). Experiment unchanged: ~55-reg working set compiles
// spill-free; actual VGPR <=64 -> 2 blocks/CU = 32 waves/CU.
// 8 lanes/row (qt,jh), 128 lane-groups x 9 rows = 1152.
// ============================================================================
#define LOADROW(Q0, Q1, Q2, Q3, Q4, ROW)                                      \
    {                                                                         \
        const uint32* p_ = ubase + (size_t)(ROW) * 80;                        \
        Q0 = *(const uint2*)(p_);     Q1 = *(const uint2*)(p_ + 2);           \
        Q2 = *(const uint2*)(p_ + 4); Q3 = *(const uint2*)(p_ + 6);           \
        Q4 = *(const uint2*)(p_ + 8);                                         \
    }

#define PROCESS(Q0, Q1, Q2, Q3, Q4)                                           \
    {                                                                         \
        uint32 ur[10];                                                        \
        ur[0] = Q0.x; ur[1] = Q0.y; ur[2] = Q1.x; ur[3] = Q1.y;               \
        ur[4] = Q2.x; ur[5] = Q2.y; ur[6] = Q3.x; ur[7] = Q3.y;               \
        ur[8] = Q4.x; ur[9] = Q4.y;                                           \
        float cj[5];                                                          \
        if (it == 0) {                                                        \
            _Pragma("unroll")                                                 \
            for (int jl = 0; jl < 5; ++jl) cj[jl] = 0.1f;                     \
        } else {                                                              \
            float sum = 0.0f;                                                 \
            _Pragma("unroll")                                                 \
            for (int jl = 0; jl < 5; ++jl) {                                  \
                float2 ua = unpackf16(ur[2 * jl]);                            \
                float2 ub = unpackf16(ur[2 * jl + 1]);                        \
                float4 vv = *(const float4*)&vls[vbase + 16 * jl];            \
                float pj = ua.x * vv.x + ua.y * vv.y + ub.x * vv.z + ub.y * vv.w; \
                pj += __shfl_xor(pj, 1);                                      \
                pj += __shfl_xor(pj, 2);                                      \
                float e = __expf(pj);                                         \
                cj[jl] = e;                                                   \
                sum += e;                                                     \
            }                                                                 \
            sum += __shfl_xor(sum, 4);                                        \
            float inv = 1.0f / sum;                                           \
            _Pragma("unroll")                                                 \
            for (int jl = 0; jl < 5; ++jl) cj[jl] *= inv;                     \
        }                                                                     \
        _Pragma("unroll")                                                     \
        for (int jl = 0; jl < 5; ++jl) {                                      \
            float2 ua = unpackf16(ur[2 * jl]);                                \
            float2 ub = unpackf16(ur[2 * jl + 1]);                            \
            acc[4 * jl + 0] += cj[jl] * ua.x;                                 \
            acc[4 * jl + 1] += cj[jl] * ua.y;                                 \
            acc[4 * jl + 2] += cj[jl] * ub.x;                                 \
            acc[4 * jl + 3] += cj[jl] * ub.y;                                 \
        }                                                                     \
    }

__global__ __launch_bounds__(1024) void routing_kernel(const uint32* __restrict__ u,
                                                       float* __restrict__ outp) {
    const int b    = blockIdx.x;
    const int t    = threadIdx.x;
    const int w    = t >> 6;          // wave 0..15
    const int l    = t & 63;
    const int qt   = l & 3;           // o-quarter
    const int jh   = (l >> 2) & 1;    // capsule half
    const int mloc = l >> 3;          // group within wave (0..7)
    const int g    = qt * 2 + jh;     // u32-group in row

    __shared__ float sl[NJO];     // s accumulator
    __shared__ float vls[NJO];    // current v-sum (fp32), read by dot
    __shared__ float vaccl[NJO];  // running v0+v1 (fp32)

    for (int i = t; i < NJO; i += 1024) sl[i] = 0.0f;
    __syncthreads();

    const uint32* ubase = u + (size_t)b * (NR * 80) + g * 10;
    const int vbase = jh * 80 + qt * 4;     // vls[16*(jh*5+jl) + 4*qt]
    const int gid   = w * 8 + mloc;         // lane-group 0..127; rows gid + 128*c9

#pragma unroll 1
    for (int it = 0; it < 3; ++it) {
        float acc[20];
#pragma unroll
        for (int i = 0; i < 20; ++i) acc[i] = 0.0f;

#pragma unroll 1
        for (int c9 = 0; c9 < 9; ++c9) {
            uint2 q0, q1, q2, q3, q4;
            LOADROW(q0, q1, q2, q3, q4, gid + (size_t)c9 * 128)
            PROCESS(q0, q1, q2, q3, q4)
        }

        // ---- reduce-scatter among the 8 same-(qt,jh) lanes (masks 8,16,32) ----
        float a[12];
        {
            const int bit = (l >> 3) & 1;
#pragma unroll
            for (int i = 0; i < 12; ++i) {
                float lo = acc[i];
                float hi = (i + 12 < 20) ? acc[i + 12] : 0.0f;
                float send = bit ? lo : hi;
                float recv = __shfl_xor(send, 8);
                a[i] = (bit ? hi : lo) + recv;
            }
        }
#pragma unroll
        for (int st = 1; st < 3; ++st) {
            const int h = 12 >> st;              // 6,3
            const int bit = (l >> (3 + st)) & 1;
#pragma unroll
            for (int i = 0; i < 6; ++i) {
                if (i < h) {
                    float send = bit ? a[i] : a[i + h];
                    float recv = __shfl_xor(send, 8 << st);
                    a[i] = (bit ? a[i + h] : a[i]) + recv;
                }
            }
        }
        const int base = 3 * (__brev((uint32)mloc) >> 29);
#pragma unroll
        for (int i = 0; i < 3; ++i) {
            int aidx = base + i;
            if (aidx < 20) {
                int jl = aidx >> 2, e = aidx & 3;
                atomicAdd(&sl[16 * (jh * 5 + jl) + 4 * qt + e], a[i]);
            }
        }
        __syncthreads();

        // ---- in-block squash: thread p<80 owns o-pair (2p, 2p+1) ----
        if (t < 80) {
            float2 sv = *(const float2*)&sl[2 * t];
            float sq = sv.x * sv.x + sv.y * sv.y;
#pragma unroll
            for (int off = 1; off < 8; off <<= 1) sq += __shfl_xor(sq, off, 8);
            float scale = (sq / (1.0f + sq)) * rsqrtf(sq + 1e-8f);
            float vx = sv.x * scale, vy = sv.y * scale;
            if (it == 2) {
                *(float2*)&outp[b * NJO + 2 * t] = make_float2(vx, vy);
            } else {
                float2 va;
                if (it == 0) va = make_float2(vx, vy);
                else {
                    va = *(const float2*)&vaccl[2 * t];
                    va.x += vx; va.y += vy;
                }
                *(float2*)&vaccl[2 * t] = va;
                *(float2*)&vls[2 * t]   = va;
            }
        }
        __syncthreads();
        if (it < 2) {
            for (int i = t; i < NJO; i += 1024) sl[i] = 0.0f;
            __syncthreads();
        }
    }
}

// ============================================================================
extern "C" void kernel_launch(void* const* d_in, const int* in_sizes, int n_in,
                              void* d_out, int out_size, void* d_ws, size_t ws_size,
                              hipStream_t stream) {
    (void)in_sizes; (void)n_in; (void)out_size; (void)ws_size;

    const float* x = (const float*)d_in[0];  // [B,R,C]
    const float* W = (const float*)d_in[1];  // [R,J,O,C]
    float* out = (float*)d_out;              // [B,J,O,1] fp32

    char* ws = (char*)d_ws;
    const size_t XBYTES = (size_t)NR * NB * NC * 4;   // 18,874,368
    float*  xT = (float*)ws;
    uint32* u  = (uint32*)(ws + XBYTES);              // [B,R,80] f16 pairs

    xpose_kernel<<<dim3(NR / 16, NB / 64), 256, 0, stream>>>(x, xT);
    uhat_kernel<<<NR, 320, 0, stream>>>(xT, W, u);
    routing_kernel<<<NB, 1024, 0, stream>>>(u, out);
}